// Round 8
// baseline (1633.845 us; speedup 1.0000x reference)
//
#include <hip/hip_runtime.h>

// Persistent-CG, full-row decomposition. R6 lesson: sc1 write-through does NOT
// allocate L3 -> every cross-block datum (W0 1.1MB/iter, r, slots) made an HBM
// round trip; 4 handoffs + 2 barriers/iter = ~33us/iter with only ~6us VALU.
// R7: block owns 16 FULL rows of K (16x4096 = 128 VGPR/thread, thread = 8 rows
// x 16 k). w = K[rows,:]@r complete in-block => W0 gone; dp/gp local; p/s/x in
// registers (zero traffic). Remaining cross-block: 34-float slots + 272-float
// r publish per block + r broadcast read (16KB col-slabs double-buffered via
// LDS; 278KB/iter unique HBM, L3 serves the 64x broadcast). 2 barriers/iter
// (R6-verified gridbar, unchanged).

#define NN   4096
#define TT   17
#define PP   16
#define NTOT (NN*TT)
#define NIT  47
#define NBLK 256              // 1 block/CU, cooperative co-residency
#define NTHR 512              // 8 waves
#define EPB  272              // 17 cols x 16 own rows = owner elements per block

// ws float offsets
#define O_SSQ  0                    // [16][64] setup ssq partials (sc1 path)
#define O_SLOT (O_SSQ + 16*64)      // [256][64] per-iter dot slots (sc1 path)
#define O_BAR  (O_SLOT + NBLK*64)   // flags[256] + go replicas at 256+32*i
#define O_R    (O_BAR + 576)        // r (sc1 path)

#define AGENT __HIP_MEMORY_SCOPE_AGENT
#define RLX   __ATOMIC_RELAXED

typedef float f32x4 __attribute__((ext_vector_type(4)));

__global__ void k_bzero(float* __restrict__ ws) {
    if (threadIdx.x < 576) ((unsigned*)(ws + O_BAR))[threadIdx.x] = 0u;
}

// Store-only monotonic grid barrier (R6-verified). Entry waitcnt drains sc1
// stores to the coherence point; consumers use sc1 loads -> no cache fences.
__device__ __forceinline__ void gridbar(unsigned* bar, int phase, int b) {
    const unsigned target = (unsigned)(phase + 1);
    asm volatile("s_waitcnt vmcnt(0)" ::: "memory");
    __syncthreads();
    if (b == 0) {
        if (threadIdx.x >= 1 && threadIdx.x < NBLK) {
            while (__hip_atomic_load(&bar[threadIdx.x], RLX, AGENT) < target)
                __builtin_amdgcn_s_sleep(1);
        }
        __syncthreads();
        if (threadIdx.x < 8)
            __hip_atomic_store(&bar[256 + threadIdx.x*32], target, RLX, AGENT);
    } else {
        if (threadIdx.x == 0) {
            __hip_atomic_store(&bar[b], target, RLX, AGENT);
            while (__hip_atomic_load(&bar[256 + (b & 7)*32], RLX, AGENT) < target)
                __builtin_amdgcn_s_sleep(1);
        }
    }
    __syncthreads();
}

__global__ __launch_bounds__(NTHR, 2)
void k_cg(const float* __restrict__ Km, const float* __restrict__ yv,
          const float* __restrict__ Zm, const float* __restrict__ noise,
          float* __restrict__ out, float* __restrict__ ws) {
    __shared__ __align__(16) float rslab[2][NN];     // 32 KB r col double-buffer
    __shared__ float4 p2a[8*TT*17];                  // wave partials rows 0-3
    __shared__ float4 p2b[8*TT*17];                  // rows 4-7 (pad 17)
    __shared__ float rst[TT][16], wst[TT][16];       // own-row r and w = K@r
    __shared__ float sm[8][64];
    __shared__ float s_scale[TT], s_rhs[TT], s_al[TT], s_be[TT], s_ap[TT], s_gp[TT];
    __shared__ float redd[TT];

    const int t = threadIdx.x, b = blockIdx.x;
    const int lane = t & 63, w = t >> 6;             // 8 waves
    const int h = t >> 8;                            // row-half 0/1 (8 rows each)
    const int kslot = t & 255;                       // k-slot: 16 floats/thread
    unsigned* bar = (unsigned*)(ws + O_BAR);
    float* r_ = ws + O_R;
    const float s2 = noise[0]*noise[0];
    int ph = 0;
    float pr = 0.f, sr = 0.f, xr = 0.f;              // per-thread CG state (t<272)

    // ---- one-time: K rows b*16+h*8+rr, k = g*1024 + kslot*4 -> 128 VGPRs ----
    float4 kreg[8][4];
    {
        const float* Kb = Km + (size_t)(b*16 + h*8)*NN + kslot*4;
        #pragma unroll
        for (int rr = 0; rr < 8; ++rr)
            #pragma unroll
            for (int g = 0; g < 4; ++g)
                kreg[rr][g] = *(const float4*)(Kb + (size_t)rr*NN + g*1024);
    }

    // ---- setup: per-column sum-of-squares partials (blocks 0..15) ----
    if (t < TT) redd[t] = 0.f;
    __syncthreads();
    if (b < 16 && t < 256) {
        int n = b*256 + t;
        float yy = yv[n];
        atomicAdd(&redd[0], yy*yy);
        #pragma unroll
        for (int j = 0; j < PP; ++j) { float v = Zm[n*PP + j]; atomicAdd(&redd[j+1], v*v); }
    }
    __syncthreads();
    if (b < 16 && t < TT)
        __hip_atomic_store(&ws[O_SSQ + b*64 + t], redd[t], RLX, AGENT);
    gridbar(bar, ph++, b);

    // ---- setup: scale/rhs replicated; r0 at own elements (c, b*16+i) ----
    if (t < TT) {
        float s = 0.f;
        #pragma unroll
        for (int i = 0; i < 16; ++i)
            s += __hip_atomic_load(&ws[O_SSQ + i*64 + t], RLX, AGENT);
        float scale, rh;
        if (t == 0) {
            rh = sqrtf(s); if (rh < 1e-10f) rh = 1.f;
            scale = 1.f/rh;
        } else {
            float zn = sqrtf(s);
            float bn = zn/(zn + 1e-10f);
            rh = (bn < 1e-10f) ? 1.f : bn;
            scale = 1.f/((zn + 1e-10f)*rh);
        }
        s_scale[t] = scale; s_rhs[t] = rh;
    }
    __syncthreads();
    if (t < EPB) {
        int c = t >> 4, i = t & 15, n = b*16 + i;
        float raw = (c == 0) ? yv[n] : Zm[n*PP + (c-1)];
        __hip_atomic_store(&r_[c*NN + n], raw * s_scale[c], RLX, AGENT);
    }
    gridbar(bar, ph++, b);

    // ---- 47 CG iterations ----
    for (int it = 0; it < NIT; ++it) {
        if (t < EPB) wst[t >> 4][t & 15] = 0.f;
        // prologue: stage col 0 (16 KB) into rslab[0]
        {
            const float* p0 = r_ + t*8;
            const float* p1 = p0 + 4;
            f32x4 a0, a1;
            asm volatile(
                "global_load_dwordx4 %0, %2, off sc1\n\t"
                "global_load_dwordx4 %1, %3, off sc1\n\t"
                "s_waitcnt vmcnt(0)"
                : "=&v"(a0), "=&v"(a1) : "v"(p0), "v"(p1) : "memory");
            *(f32x4*)&rslab[0][t*8]     = a0;
            *(f32x4*)&rslab[0][t*8 + 4] = a1;
        }
        __syncthreads();
        int cur = 0;

        for (int c = 0; c < TT; ++c) {
            // issue next col's sc1 loads early (latency hides under compute)
            f32x4 sA, sB;
            const bool more = (c + 1 < TT);
            if (more) {
                const float* p0 = r_ + (c+1)*NN + t*8;
                const float* p1 = p0 + 4;
                asm volatile(
                    "global_load_dwordx4 %0, %2, off sc1\n\t"
                    "global_load_dwordx4 %1, %3, off sc1"
                    : "=&v"(sA), "=&v"(sB) : "v"(p0), "v"(p1) : "memory");
            }
            if (t < 16) rst[c][t] = rslab[cur][b*16 + t];   // own-row r capture

            // compute: 4x ds_read_b128 + 128 fmac into 8 row-accs
            float acc[8];
            #pragma unroll
            for (int rr = 0; rr < 8; ++rr) acc[rr] = 0.f;
            const float* rc = &rslab[cur][kslot*4];
            #pragma unroll
            for (int g = 0; g < 4; ++g) {
                float4 rv = *(const float4*)(rc + g*1024);
                #pragma unroll
                for (int rr = 0; rr < 8; ++rr)
                    acc[rr] += kreg[rr][g].x*rv.x + kreg[rr][g].y*rv.y
                             + kreg[rr][g].z*rv.z + kreg[rr][g].w*rv.w;
            }
            // 2-stage butterfly: 64 lanes -> 16 lane-classes
            #pragma unroll
            for (int rr = 0; rr < 8; ++rr) {
                float v2 = acc[rr];
                v2 += __shfl_xor(v2, 32, 64);
                v2 += __shfl_xor(v2, 16, 64);
                acc[rr] = v2;
            }
            if (lane < 16) {
                p2a[(w*TT + c)*17 + lane] = make_float4(acc[0], acc[1], acc[2], acc[3]);
                p2b[(w*TT + c)*17 + lane] = make_float4(acc[4], acc[5], acc[6], acc[7]);
            }
            if (more) {
                asm volatile("s_waitcnt vmcnt(0)" ::: "memory");
                __builtin_amdgcn_sched_barrier(0);
                *(f32x4*)&rslab[cur^1][t*8]     = sA;
                *(f32x4*)&rslab[cur^1][t*8 + 4] = sB;
                __syncthreads();                 // next slab ready for everyone
                cur ^= 1;
            }
        }
        __syncthreads();                         // last col's p2 writes visible

        // finish: (w2,c2) sums 16 lane-classes -> quarter partial of w; LDS
        // atomic-add combines the 4 k-quarters into wst[c2][row]
        if (t < 8*TT) {
            int w2 = t / TT, c2 = t % TT, h2 = w2 >> 2;
            float4 sa = make_float4(0.f,0.f,0.f,0.f), sb = make_float4(0.f,0.f,0.f,0.f);
            #pragma unroll
            for (int i = 0; i < 16; ++i) {
                float4 u = p2a[(w2*TT + c2)*17 + i];
                sa.x += u.x; sa.y += u.y; sa.z += u.z; sa.w += u.w;
                float4 v2 = p2b[(w2*TT + c2)*17 + i];
                sb.x += v2.x; sb.y += v2.y; sb.z += v2.z; sb.w += v2.w;
            }
            float* wr = &wst[c2][h2*8];
            atomicAdd(&wr[0], sa.x); atomicAdd(&wr[1], sa.y);
            atomicAdd(&wr[2], sa.z); atomicAdd(&wr[3], sa.w);
            atomicAdd(&wr[4], sb.x); atomicAdd(&wr[5], sb.y);
            atomicAdd(&wr[6], sb.z); atomicAdd(&wr[7], sb.w);
        }
        __syncthreads();

        // dp/gp fully local (own rows): publish 34 floats
        if (t < TT) {
            float dp = 0.f, gp = 0.f;
            #pragma unroll
            for (int i = 0; i < 16; ++i) {
                float rv = rst[t][i];
                dp += rv * wst[t][i];
                gp += rv * rv;
            }
            __hip_atomic_store(&ws[O_SLOT + b*64 + t], dp, RLX, AGENT);
            __hip_atomic_store(&ws[O_SLOT + b*64 + 32 + t], gp, RLX, AGENT);
        }
        gridbar(bar, ph++, b);

        // phase B: replicated slot reduce -> alpha/beta; pure-register update
        {
            int seg = t >> 6, j = t & 63;
            float s = 0.f;
            if (j < TT || (j >= 32 && j < 32 + TT)) {
                #pragma unroll
                for (int i = 0; i < 32; ++i)
                    s += __hip_atomic_load(&ws[O_SLOT + (seg*32 + i)*64 + j],
                                           RLX, AGENT);
            }
            sm[seg][j] = s;
        }
        __syncthreads();
        if (t < TT) {
            float del = 0.f, gam = 0.f;
            #pragma unroll
            for (int g = 0; g < 8; ++g) { del += sm[g][t]; gam += sm[g][32 + t]; }
            float delta = del + s2*gam;          // r^T (K + s2 I) r
            float beta = 0.f, D = delta;
            if (it > 0) {
                float gpv = s_gp[t];
                beta = (fabsf(gpv) < 1e-30f) ? 0.f : gam/gpv;
                float apv = s_ap[t];
                D = delta - ((fabsf(apv) < 1e-30f) ? 0.f : beta*gam/apv);
            }
            float alpha = (fabsf(D) < 1e-30f) ? 0.f : gam/D;
            s_al[t] = alpha; s_be[t] = beta; s_ap[t] = alpha; s_gp[t] = gam;
        }
        __syncthreads();
        if (t < EPB) {
            int c = t >> 4, i = t & 15;
            float al = s_al[c], be = s_be[c];
            float rv = rst[c][i];
            float wv = wst[c][i] + s2*rv;
            pr = rv + be*pr;
            sr = wv + be*sr;
            xr = xr + al*pr;
            float rn = rv - al*sr;
            __hip_atomic_store(&r_[c*NN + b*16 + i], rn, RLX, AGENT);
            if (it == NIT-1) out[(b*16 + i)*TT + c] = xr * s_rhs[c];
        }
        gridbar(bar, ph++, b);
    }
}

extern "C" void kernel_launch(void* const* d_in, const int* in_sizes, int n_in,
                              void* d_out, int out_size, void* d_ws, size_t ws_size,
                              hipStream_t stream) {
    const float* Km    = (const float*)d_in[0];
    const float* yv    = (const float*)d_in[1];
    const float* Zm    = (const float*)d_in[2];
    const float* noise = (const float*)d_in[3];
    float* out = (float*)d_out;
    float* ws  = (float*)d_ws;

    k_bzero<<<1, 576, 0, stream>>>(ws);
    void* args[] = {(void*)&Km, (void*)&yv, (void*)&Zm, (void*)&noise,
                    (void*)&out, (void*)&ws};
    (void)hipLaunchCooperativeKernel((const void*)k_cg, dim3(NBLK), dim3(NTHR),
                                     args, 0, stream);
}